// Round 12
// baseline (71.436 us; speedup 1.0000x reference)
//
#include <hip/hip_runtime.h>
#include <math.h>

#define BB 8
#define SS 4096
#define DD 1024
#define HH 16

typedef __attribute__((ext_vector_type(4))) float f32x4;
typedef __fp16 fp16x2 __attribute__((ext_vector_type(2)));
typedef _Float16 half8v __attribute__((ext_vector_type(8)));

// ws layout (no aliasing):
//   plog    [BB][SS][HH] fp32 = 2 MB   @ 0      (scaled+masked logits)
//   partial [32][BB][HH][DD]  = 16 MB  @ 6 MB
//   wh16/wl16 fp16 frag streams 32+32 KB @ 22 MB
//   bred    [BB][64][HH] float2 = 64 KB @ 23 MB (per-64-row-chunk softmax partials)

__device__ __forceinline__ void sm_merge(float& m, float& z, float om, float oz) {
  float nm = fmaxf(m, om);
  if (nm > -INFINITY)
    z = z * __expf(m - nm) + oz * __expf(om - nm);
  m = nm;
}

// K0: W fp16 hi/lo frag streams. Element e of lane l at K-step t <-> k =
// t*32 + (l>>4)*8 + e, col h = l&15. Layout [t][lane][e], t = 0..31.
__global__ __launch_bounds__(256) void k_prepw(
    const float* __restrict__ W, ushort* __restrict__ wh16, ushort* __restrict__ wl16) {
  int i = blockIdx.x * 256 + threadIdx.x;  // 16384
  int t = i >> 9;
  int l = (i >> 3) & 63;
  int e = i & 7;
  int d = t * 32 + (l >> 4) * 8 + e;
  int h = l & 15;
  float w = W[d * HH + h];
  _Float16 wh = (_Float16)w;               // RNE
  _Float16 wl = (_Float16)(w - (float)wh); // residual
  union { _Float16 f; ushort u; } ch, cl;
  ch.f = wh; cl.f = wl;
  wh16[i] = ch.u;
  wl16[i] = cl.u;
}

// K1 v7: R10 pipeline with 512 B islands. Chunk = 128 floats of K; each
// XLOAD instr covers 2 rows x 512 B contiguous. LDS [16][32] float4 x2 buf
// = 64 KB/block (2 blocks/CU). Wave-private -> no barriers.
// grid 512 (= 8 b x 64 s-tiles of 64 rows), block 256 = 4 independent waves.
#define XLOAD(dst, c)                                                          \
  _Pragma("unroll") for (int k = 0; k < 8; ++k) {                              \
    int row = k * 2 + (lane >> 5);                                             \
    dst[k] = *reinterpret_cast<const float4*>(                                 \
        xw + (size_t)row * DD + (c) * 128 + (lane & 31) * 4);                  \
  }
#define XSTAGE(src, c)                                                         \
  _Pragma("unroll") for (int k = 0; k < 8; ++k) {                              \
    int row = k * 2 + (lane >> 5);                                             \
    lds4[(c) & 1][wv][row][(lane & 31) ^ (row & 7)] = src[k];                  \
  }
#define WLOAD(c)                                                               \
  _Pragma("unroll") for (int j = 0; j < 4; ++j) {                              \
    whf[(c) & 1][j] = bhp[(4 * (c) + j) * 64];                                 \
    wlf[(c) & 1][j] = blp[(4 * (c) + j) * 64];                                 \
  }

__global__ __launch_bounds__(256, 2) void k_logits(
    const float* __restrict__ x, const ushort* __restrict__ wh16,
    const ushort* __restrict__ wl16, const int* __restrict__ mask,
    float* __restrict__ plog, float2* __restrict__ bred) {
  __shared__ float4 lds4[2][4][16][32];  // [buf][wave][row][unit], 64 KB
  __shared__ float2 smch[4][16];

  const int tid = threadIdx.x;
  const int lane = tid & 63;
  const int wv = __builtin_amdgcn_readfirstlane(tid >> 6);
  const int b = blockIdx.x >> 6;
  const int tile = blockIdx.x & 63;
  const int s0 = tile * 64;
  const int r15 = lane & 15;      // A row within wave tile / D col (h)
  const int kg = lane >> 4;       // k-group

  const float* xw = x + ((size_t)b * SS + s0 + wv * 16) * DD;
  const half8v* bhp = reinterpret_cast<const half8v*>(wh16) + lane;
  const half8v* blp = reinterpret_cast<const half8v*>(wl16) + lane;

  f32x4 acch = {0.f, 0.f, 0.f, 0.f};
  f32x4 accl = {0.f, 0.f, 0.f, 0.f};
  float4 st[2][8];
  half8v whf[2][4], wlf[2][4];

  // prologue: 2-deep x prefetch; stage chunk 0; W chunks 0,1
  XLOAD(st[0], 0);
  XLOAD(st[1], 1);
  XSTAGE(st[0], 0);
  WLOAD(0);
  WLOAD(1);

#pragma unroll
  for (int c = 0; c < 8; ++c) {
    if (c < 6) { XLOAD(st[c & 1], c + 2); }  // st[c&1]'s chunk is already in LDS

#pragma unroll
    for (int t4 = 0; t4 < 4; ++t4) {
      const int u0 = t4 * 8 + kg * 2;
      float4 va = lds4[c & 1][wv][r15][u0 ^ (r15 & 7)];
      float4 vb = lds4[c & 1][wv][r15][(u0 + 1) ^ (r15 & 7)];
      union { fp16x2 h2[4]; half8v h8; } ax;
      ax.h2[0] = __builtin_amdgcn_cvt_pkrtz(va.x, va.y);
      ax.h2[1] = __builtin_amdgcn_cvt_pkrtz(va.z, va.w);
      ax.h2[2] = __builtin_amdgcn_cvt_pkrtz(vb.x, vb.y);
      ax.h2[3] = __builtin_amdgcn_cvt_pkrtz(vb.z, vb.w);
      acch = __builtin_amdgcn_mfma_f32_16x16x32_f16(ax.h8, whf[c & 1][t4], acch, 0, 0, 0);
      accl = __builtin_amdgcn_mfma_f32_16x16x32_f16(ax.h8, wlf[c & 1][t4], accl, 0, 0, 0);
    }

    if (c < 6) { WLOAD(c + 2); }               // whf[c&1] just consumed
    if (c < 7) { XSTAGE(st[(c + 1) & 1], c + 1); }
  }

  // epilogue: masked scaled logits -> plog; chunk (m,Z) partials -> bred.
  // D layout: col = r15 (h), row = kg*4+q (m89-verified; passed R2..R10)
  float lv[4];
  float* ob = plog + ((size_t)b * SS + s0 + wv * 16) * HH;
#pragma unroll
  for (int q = 0; q < 4; ++q) {
    int srw = kg * 4 + q;
    int msk = mask[b * SS + s0 + wv * 16 + srw];
    float v = (acch[q] + accl[q]) * 0.125f;
    lv[q] = msk ? v : -INFINITY;
    ob[(size_t)srw * HH + r15] = lv[q];
  }
  float ml = fmaxf(fmaxf(lv[0], lv[1]), fmaxf(lv[2], lv[3]));
  float zl = 0.f;
  if (ml > -INFINITY) {
#pragma unroll
    for (int q = 0; q < 4; ++q) zl += __expf(lv[q] - ml);
  }
  // merge across the 4 k-groups (lanes sharing r15)
#pragma unroll
  for (int off = 16; off < 64; off <<= 1) {
    float om = __shfl_xor(ml, off, 64);
    float oz = __shfl_xor(zl, off, 64);
    sm_merge(ml, zl, om, oz);
  }
  if (kg == 0) smch[wv][r15] = make_float2(ml, zl);
  __syncthreads();
  if (tid < 16) {
    float2 p0 = smch[0][tid];
    float m = p0.x, z = p0.y;
#pragma unroll
    for (int w = 1; w < 4; ++w) {
      float2 pw = smch[w][tid];
      sm_merge(m, z, pw.x, pw.y);
    }
    bred[((size_t)b * 64 + tile) * HH + tid] = make_float2(m, z);
  }
}

// K3: pooling with inline softmax finalize (grid 512 = 8b x 32sc x 2dh).
__global__ __launch_bounds__(256) void k_pool(
    const float* __restrict__ x, const float* __restrict__ plog,
    const float2* __restrict__ bred, const int* __restrict__ mask,
    float* __restrict__ partial) {
  __shared__ float wl[128][16];
  __shared__ float fm[16], fz[16];
  const int tid = threadIdx.x;
  const int dh = blockIdx.x & 1;
  const int sc = (blockIdx.x >> 1) & 31;
  const int b = blockIdx.x >> 6;
  const int s0 = sc * 128;

  if (tid < 16) {
    float m = -INFINITY, z = 0.f;
#pragma unroll 4
    for (int c = 0; c < 64; ++c) {
      float2 p = bred[((size_t)b * 64 + c) * HH + tid];
      sm_merge(m, z, p.x, p.y);
    }
    fm[tid] = m;
    fz[tid] = (z > 0.f) ? 1.0f / z : 0.f;
  }
  __syncthreads();

  const float4* p0 = reinterpret_cast<const float4*>(plog + ((size_t)b * SS + s0) * HH);
  const int* mb = mask + b * SS + s0;
#pragma unroll
  for (int k = 0; k < 2; ++k) {
    int f = k * 256 + tid;  // float4 over [128][16]
    float4 va = p0[f];
    int msk = mb[f >> 2];
    int hb = (f & 3) * 4;
    float4 w;
    w.x = msk ? __expf(va.x - fm[hb + 0]) * fz[hb + 0] : 0.f;
    w.y = msk ? __expf(va.y - fm[hb + 1]) * fz[hb + 1] : 0.f;
    w.z = msk ? __expf(va.z - fm[hb + 2]) * fz[hb + 2] : 0.f;
    w.w = msk ? __expf(va.w - fm[hb + 3]) * fz[hb + 3] : 0.f;
    *reinterpret_cast<float4*>(&wl[0][0] + f * 4) = w;
  }
  __syncthreads();

  float2 acc[HH];
#pragma unroll
  for (int h = 0; h < HH; ++h) acc[h] = make_float2(0.f, 0.f);

  const float* xb = x + ((size_t)b * SS + s0) * DD + dh * 512 + tid * 2;
  for (int s = 0; s < 128; ++s) {
    float2 xv = *reinterpret_cast<const float2*>(xb + (size_t)s * DD);
    const float4* wrow = reinterpret_cast<const float4*>(wl[s]);
    float4 wa = wrow[0], wb_ = wrow[1], wc = wrow[2], wd = wrow[3];
    float wvv[16] = {wa.x, wa.y, wa.z, wa.w, wb_.x, wb_.y, wb_.z, wb_.w,
                     wc.x, wc.y, wc.z, wc.w, wd.x, wd.y, wd.z, wd.w};
#pragma unroll
    for (int h = 0; h < HH; ++h) {
      float w = wvv[h];
      acc[h].x += w * xv.x;
      acc[h].y += w * xv.y;
    }
  }

  float* pb = partial + ((size_t)sc * BB + b) * (HH * DD) + dh * 512 + tid * 2;
#pragma unroll
  for (int h = 0; h < HH; ++h)
    *reinterpret_cast<float2*>(pb + (size_t)h * DD) = acc[h];
}

// K4: reduce 32 s-chunk partials. grid 512, block 256.
__global__ __launch_bounds__(256) void k_reduce(
    const float* __restrict__ partial, float* __restrict__ out) {
  const int idx = blockIdx.x * 256 + threadIdx.x;
  float s = 0.f;
#pragma unroll
  for (int c = 0; c < 32; ++c) s += partial[(size_t)c * (BB * HH * DD) + idx];
  out[idx] = s;
}

extern "C" void kernel_launch(void* const* d_in, const int* in_sizes, int n_in,
                              void* d_out, int out_size, void* d_ws, size_t ws_size,
                              hipStream_t stream) {
  const float* x = (const float*)d_in[0];     // [8][4096][1024] fp32
  const float* W = (const float*)d_in[1];     // [1024][16] fp32
  const int* mask = (const int*)d_in[2];      // [8][4096] int32
  float* out = (float*)d_out;                 // [8][16384] fp32

  char* ws = (char*)d_ws;
  float* plog    = (float*)ws;                                   // 2 MB
  float* partial = (float*)(ws + (size_t)6 * 1024 * 1024);       // 16 MB
  ushort* wh16   = (ushort*)(ws + (size_t)22 * 1024 * 1024);     // 32 KB
  ushort* wl16   = (ushort*)(ws + (size_t)22 * 1024 * 1024 + 32 * 1024);
  float2* bred   = (float2*)(ws + (size_t)23 * 1024 * 1024);     // 64 KB

  k_prepw<<<64, 256, 0, stream>>>(W, wh16, wl16);
  k_logits<<<512, 256, 0, stream>>>(x, wh16, wl16, mask, plog, bred);
  k_pool<<<512, 256, 0, stream>>>(x, plog, bred, mask, partial);
  k_reduce<<<512, 256, 0, stream>>>(partial, out);
}